// Round 3
// baseline (348.669 us; speedup 1.0000x reference)
//
#include <hip/hip_runtime.h>
#include <hip/hip_bf16.h>

#define TSEQ 2048
#define CDIM 2048
#define NH   16
#define NKV  4
#define HDIM 128
#define BATCH 2
#define MROWS (BATCH*TSEQ)   // 4096
#define KVC   (NKV*HDIM)     // 512
#define QKVC  (CDIM + 2*KVC) // 3072: fused qkv row stride

typedef short bf16x8 __attribute__((ext_vector_type(8)));
typedef float f32x4  __attribute__((ext_vector_type(4)));

typedef const __attribute__((address_space(1))) void* gptr_t;
typedef __attribute__((address_space(3))) void* sptr_t;

__device__ inline void async16(const __hip_bfloat16* g, __hip_bfloat16* l) {
  __builtin_amdgcn_global_load_lds((gptr_t)g, (sptr_t)l, 16, 0, 0);
}

__device__ inline f32x4 mfma16(bf16x8 a, bf16x8 b, f32x4 c) {
  return __builtin_amdgcn_mfma_f32_16x16x32_bf16(a, b, c, 0, 0, 0);
}

__device__ inline float bfbits2f(unsigned short u) {
  return __uint_as_float(((unsigned)u) << 16);
}

// LDS XOR-swizzles: break row-stride bank aliasing for 16B fragment access.
__device__ inline int swz128(int row, int col) {  // rows of 128 bf16
  return row*128 + (((col >> 3) ^ (row & 15)) << 3) + (col & 7);
}
__device__ inline int swz64(int row, int col) {   // rows of 64 bf16
  return row*64 + ((((col >> 3) ^ row) & 7) << 3) + (col & 7);
}

// ---- dtype canary: inputs bf16 (flag=1) or f32 (flag=0) ----
__global__ void canary(const void* __restrict__ x, int* __restrict__ flag) {
  __shared__ int cnt[256];
  int tid = threadIdx.x;
  const unsigned short* u = (const unsigned short*)x;
  int c = 0;
#pragma unroll
  for (int i = 0; i < 4; ++i) {
    float a = fabsf(bfbits2f(u[(tid*4 + i)*2]));
    if (a >= 1e-6f && a <= 1e3f) c++;
  }
  cnt[tid] = c;
  __syncthreads();
  for (int s = 128; s > 0; s >>= 1) {
    if (tid < s) cnt[tid] += cnt[tid + s];
    __syncthreads();
  }
  if (tid == 0) *flag = (cnt[0] > 512) ? 1 : 0;
}

// ---- canonize ALL inputs in one launch; Wq/Wk/Wv land contiguously ----
// Segments (2048-elem blocks): x:4096 | Wq:2048 | Wk:512 | Wv:512 | Wo:2048 | gain:1
__global__ __launch_bounds__(256) void canonize_all(
    const void* __restrict__ xs,  const void* __restrict__ wqs,
    const void* __restrict__ wks, const void* __restrict__ wvs,
    const void* __restrict__ wos, const void* __restrict__ gs,
    __hip_bfloat16* __restrict__ xd,   // [4096][2048]
    __hip_bfloat16* __restrict__ wqkv, // [3072][2048] (Wq;Wk;Wv rows)
    __hip_bfloat16* __restrict__ wod,  // [2048][2048]
    __hip_bfloat16* __restrict__ gd,   // [16]
    const int* __restrict__ flag)
{
  int blk = blockIdx.x;
  const void* src; __hip_bfloat16* dst; int base, n;
  if      (blk < 4096) { src = xs;  dst = xd;                base = blk;        n = MROWS*CDIM; }
  else if (blk < 6144) { src = wqs; dst = wqkv;              base = blk - 4096; n = CDIM*CDIM; }
  else if (blk < 6656) { src = wks; dst = wqkv + (size_t)CDIM*CDIM;            base = blk - 6144; n = KVC*CDIM; }
  else if (blk < 7168) { src = wvs; dst = wqkv + (size_t)(CDIM+KVC)*CDIM;      base = blk - 6656; n = KVC*CDIM; }
  else if (blk < 9216) { src = wos; dst = wod;               base = blk - 7168; n = CDIM*CDIM; }
  else                 { src = gs;  dst = gd;                base = 0;          n = NH; }
  int idx = base*2048 + threadIdx.x*8;
  if (idx >= n) return;
  if (*flag) {
    *(bf16x8*)&dst[idx] = *(const bf16x8*)((const __hip_bfloat16*)src + idx);
  } else {
    const float* s = (const float*)src + idx;
#pragma unroll
    for (int j = 0; j < 8; ++j) dst[idx + j] = __float2bfloat16(s[j]);
  }
}

// ---------------------------------------------------------------------------
// 256x256 BK=64 phase-split GEMM (T2 swizzle + T3/T4 counted-vmcnt + T5).
// C[m,n] = sum_k A[m,k]*B[n,k]; A row stride lda, B row stride K.
// ---------------------------------------------------------------------------
#define BK 64

__global__ __launch_bounds__(512, 2) void gemm_bt256(
    const __hip_bfloat16* __restrict__ A,
    const __hip_bfloat16* __restrict__ B,
    __hip_bfloat16* __restrict__ C,
    int M, int N, int K, int lda)
{
  __shared__ __align__(16) __hip_bfloat16 As[2][256*BK];  // 64 KiB
  __shared__ __align__(16) __hip_bfloat16 Bs[2][256*BK];  // 64 KiB
  const int tid  = threadIdx.x;
  const int wave = tid >> 6;
  const int lane = tid & 63;
  const int qd   = lane >> 4;
  const int ln   = lane & 15;
  const int m0   = blockIdx.y * 256;
  const int n0   = blockIdx.x * 256;
  const int wm   = (wave >> 2) * 128;  // 2 wave-rows
  const int wn   = (wave & 3) * 64;    // 4 wave-cols

  auto stageA = [&](int half, int buf, int kt) {
    const __hip_bfloat16* src = A + (size_t)(m0 + half*128)*lda + kt*BK;
    __hip_bfloat16* dst = &As[buf][half*128*BK];
#pragma unroll
    for (int i = 0; i < 2; ++i) {
      int c = i*512 + tid;
      int row = c >> 3, sl = c & 7;
      int gs = sl ^ (row & 7);
      async16(&src[(size_t)row*lda + gs*8], &dst[(i*512 + wave*64)*8]);
    }
  };
  auto stageB = [&](int half, int buf, int kt) {
    const __hip_bfloat16* src = B + (size_t)(n0 + half*128)*K + kt*BK;
    __hip_bfloat16* dst = &Bs[buf][half*128*BK];
#pragma unroll
    for (int i = 0; i < 2; ++i) {
      int c = i*512 + tid;
      int row = c >> 3, sl = c & 7;
      int gs = sl ^ (row & 7);
      async16(&src[(size_t)row*K + gs*8], &dst[(i*512 + wave*64)*8]);
    }
  };
  auto ldA = [&](int buf, int m, int kk) -> bf16x8 {
    int row = wm + m*16 + ln;
    return *(const bf16x8*)&As[buf][row*BK + (((kk*4 + qd) ^ (row & 7)) << 3)];
  };
  auto ldB = [&](int buf, int n, int kk) -> bf16x8 {
    int row = wn + n*16 + ln;
    return *(const bf16x8*)&Bs[buf][row*BK + (((kk*4 + qd) ^ (row & 7)) << 3)];
  };

  f32x4 acc[8][4] = {};
  const int nt = K / BK;

  stageA(0, 0, 0); stageA(1, 0, 0);
  stageB(0, 0, 0); stageB(1, 0, 0);
  if (nt > 1) {
    stageA(0, 1, 1); stageA(1, 1, 1);
    asm volatile("s_waitcnt vmcnt(4)" ::: "memory");
  } else {
    asm volatile("s_waitcnt vmcnt(0)" ::: "memory");
  }
  __builtin_amdgcn_s_barrier();

#pragma unroll 1
  for (int t = 0; t < nt; ++t) {
    const int buf = t & 1;
    bf16x8 a03[4][2], a47[4][2], b01[2][2], b23[2][2];

    // ---- P1 ----
#pragma unroll
    for (int m = 0; m < 4; ++m)
#pragma unroll
      for (int kk = 0; kk < 2; ++kk) a03[m][kk] = ldA(buf, m, kk);
#pragma unroll
    for (int n = 0; n < 2; ++n)
#pragma unroll
      for (int kk = 0; kk < 2; ++kk) b01[n][kk] = ldB(buf, n, kk);
    if (t + 1 < nt) { stageB(0, buf ^ 1, t + 1); stageB(1, buf ^ 1, t + 1); }
    __builtin_amdgcn_s_setprio(1);
#pragma unroll
    for (int m = 0; m < 4; ++m)
#pragma unroll
      for (int n = 0; n < 2; ++n)
#pragma unroll
        for (int kk = 0; kk < 2; ++kk)
          acc[m][n] = mfma16(a03[m][kk], b01[n][kk], acc[m][n]);
    __builtin_amdgcn_s_setprio(0);
    __builtin_amdgcn_s_barrier();

    // ---- P2 ----
#pragma unroll
    for (int m = 0; m < 4; ++m)
#pragma unroll
      for (int kk = 0; kk < 2; ++kk) a47[m][kk] = ldA(buf, 4 + m, kk);
    __builtin_amdgcn_s_setprio(1);
#pragma unroll
    for (int m = 0; m < 4; ++m)
#pragma unroll
      for (int n = 0; n < 2; ++n)
#pragma unroll
        for (int kk = 0; kk < 2; ++kk)
          acc[4 + m][n] = mfma16(a47[m][kk], b01[n][kk], acc[4 + m][n]);
    __builtin_amdgcn_s_setprio(0);
    __builtin_amdgcn_s_barrier();

    // ---- P3 ----
#pragma unroll
    for (int n = 0; n < 2; ++n)
#pragma unroll
      for (int kk = 0; kk < 2; ++kk) b23[n][kk] = ldB(buf, 2 + n, kk);
    __builtin_amdgcn_s_setprio(1);
#pragma unroll
    for (int m = 0; m < 4; ++m)
#pragma unroll
      for (int n = 0; n < 2; ++n)
#pragma unroll
        for (int kk = 0; kk < 2; ++kk)
          acc[m][2 + n] = mfma16(a03[m][kk], b23[n][kk], acc[m][2 + n]);
    __builtin_amdgcn_s_setprio(0);
    __builtin_amdgcn_s_barrier();

    // ---- P4 ----
    if (t + 2 < nt) { stageA(0, buf, t + 2); stageA(1, buf, t + 2); }
    __builtin_amdgcn_s_setprio(1);
#pragma unroll
    for (int m = 0; m < 4; ++m)
#pragma unroll
      for (int n = 0; n < 2; ++n)
#pragma unroll
        for (int kk = 0; kk < 2; ++kk)
          acc[4 + m][2 + n] = mfma16(a47[m][kk], b23[n][kk], acc[4 + m][2 + n]);
    __builtin_amdgcn_s_setprio(0);
    if (t + 2 < nt) asm volatile("s_waitcnt vmcnt(4)" ::: "memory");
    else            asm volatile("s_waitcnt vmcnt(0)" ::: "memory");
    __builtin_amdgcn_s_barrier();
  }

#pragma unroll
  for (int m = 0; m < 8; ++m)
#pragma unroll
    for (int n = 0; n < 4; ++n) {
      int row = m0 + wm + m*16 + qd*4;
      int col = n0 + wn + n*16 + ln;
#pragma unroll
      for (int r = 0; r < 4; ++r)
        C[(size_t)(row + r)*N + col] = __float2bfloat16(acc[m][n][r]);
    }
}

// Output GEMM; epilogue dtype per flag (d_out matches input dtype).
__global__ __launch_bounds__(256, 2) void gemm_out(
    const __hip_bfloat16* __restrict__ A,
    const __hip_bfloat16* __restrict__ B,
    void* __restrict__ C,
    int M, int N, int K, int lda, const int* __restrict__ flag)
{
  __shared__ __align__(16) __hip_bfloat16 As[128*32];
  __shared__ __align__(16) __hip_bfloat16 Bs[128*32];
  const int tid  = threadIdx.x;
  const int wave = tid >> 6;
  const int lane = tid & 63;
  const int qd   = lane >> 4;
  const int ln   = lane & 15;
  const int m0   = blockIdx.y * 128;
  const int n0   = blockIdx.x * 128;
  const int wm   = (wave >> 1) * 64;
  const int wn   = (wave & 1) * 64;

  f32x4 acc[4][4] = {};

  for (int k0 = 0; k0 < K; k0 += 32) {
    __syncthreads();
#pragma unroll
    for (int r = 0; r < 2; ++r) {
      int e   = (r*256 + tid) * 8;
      int row = e >> 5;
      int col = e & 31;
      async16(&A[(size_t)(m0+row)*lda + k0 + col], &As[(size_t)(r*256 + wave*64)*8]);
      async16(&B[(size_t)(n0+row)*K   + k0 + col], &Bs[(size_t)(r*256 + wave*64)*8]);
    }
    __syncthreads();
    bf16x8 af[4], bfr[4];
#pragma unroll
    for (int i = 0; i < 4; ++i)
      af[i] = *(const bf16x8*)&As[(wm + i*16 + ln)*32 + qd*8];
#pragma unroll
    for (int j = 0; j < 4; ++j)
      bfr[j] = *(const bf16x8*)&Bs[(wn + j*16 + ln)*32 + qd*8];
#pragma unroll
    for (int i = 0; i < 4; ++i)
#pragma unroll
      for (int j = 0; j < 4; ++j)
        acc[i][j] = mfma16(af[i], bfr[j], acc[i][j]);
  }
  const bool isbf = (*flag != 0);
#pragma unroll
  for (int i = 0; i < 4; ++i)
#pragma unroll
    for (int j = 0; j < 4; ++j) {
      int row = m0 + wm + i*16 + qd*4;
      int col = n0 + wn + j*16 + ln;
#pragma unroll
      for (int r = 0; r < 4; ++r) {
        if (isbf) ((__hip_bfloat16*)C)[(size_t)(row + r)*N + col] = __float2bfloat16(acc[i][j][r]);
        else      ((float*)C)[(size_t)(row + r)*N + col] = acc[i][j][r];
      }
    }
}

// RMSNorm + RoPE + (gain/sqrt(HD) for q), in place on the fused qkv buffer.
__global__ __launch_bounds__(256) void prep_qk(
    __hip_bfloat16* __restrict__ qkv,  // [4096][3072]: q | k | v
    const __hip_bfloat16* __restrict__ gain)
{
  int wid  = blockIdx.x * 4 + (threadIdx.x >> 6);
  int lane = threadIdx.x & 63;
  bool isq = wid < MROWS*NH;
  int m, h;
  __hip_bfloat16* p;
  if (isq) { m = wid >> 4; h = wid & 15; p = qkv + (size_t)m*QKVC + h*HDIM; }
  else     { int w2 = wid - MROWS*NH; m = w2 >> 2; h = w2 & 3; p = qkv + (size_t)m*QKVC + CDIM + h*HDIM; }

  ushort2 raw = *(const ushort2*)((const unsigned short*)p + 2*lane);
  float e = bfbits2f(raw.x), o = bfbits2f(raw.y);
  float ss = e*e + o*o;
#pragma unroll
  for (int off = 32; off >= 1; off >>= 1) ss += __shfl_xor(ss, off);
  float rms = rsqrtf(ss * (1.0f/128.0f) + 1.1920928955078125e-07f);
  e *= rms; o *= rms;

  float theta = exp2f(-(float)(2*lane) * (1.0f/128.0f) * 13.287712379549449f);
  int t = m & (TSEQ-1);
  float fr = (float)t * theta;
  float c = cosf(fr), s = sinf(fr);
  float re = e*c - o*s;
  float ro = e*s + o*c;

  if (isq) {
    float g = bfbits2f(*(const unsigned short*)&gain[h]) * 0.08838834764831845f;
    re *= g; ro *= g;
  }
  p[2*lane]   = __float2bfloat16(re);
  p[2*lane+1] = __float2bfloat16(ro);
}

// v section of qkv [4096][3072] -> vt [B][NKV][HDIM][TSEQ]
__global__ __launch_bounds__(256) void transpose_v(
    const __hip_bfloat16* __restrict__ qkv, __hip_bfloat16* __restrict__ vt)
{
  __shared__ __hip_bfloat16 tile[32][34];
  int tx = threadIdx.x & 31;
  int ty = threadIdx.x >> 5;
  int r0 = blockIdx.x * 32;
  int c0 = blockIdx.y * 32;
#pragma unroll
  for (int i = 0; i < 4; ++i)
    tile[ty + i*8][tx] = qkv[(size_t)(r0 + ty + i*8)*QKVC + (CDIM + KVC) + c0 + tx];
  __syncthreads();
  int b = r0 >> 11;
  int t = r0 & (TSEQ-1);
  int hk = c0 >> 7;
  int d0 = c0 & (HDIM-1);
#pragma unroll
  for (int i = 0; i < 4; ++i) {
    int d = d0 + ty + i*8;
    vt[((size_t)((b*NKV + hk)*HDIM + d))*TSEQ + t + tx] = tile[tx][ty + i*8];
  }
}

// Flash attention v8: v6's balanced pairing shell + v7's 32-rows-per-wave
// arithmetic intensity. Block = 128 threads (2 waves), 64-row q-tile,
// each wave owns 32 q-rows (two 16-row sub-tiles) and reads each K/V LDS
// fragment ONCE for both sub-tiles' MFMAs. Paired segments {p, 31-p}:
// every block does exactly 33 kv-iterations -> no load-imbalance tail
// (the v7 regression). Same verified layouts throughout.
__global__ __launch_bounds__(128, 2) void attn_kernel(
    const __hip_bfloat16* __restrict__ qkv, // [B][T][3072] (read-only here)
    const __hip_bfloat16* __restrict__ vt,  // [B][NKV][HD][T]
    __hip_bfloat16* __restrict__ out)       // [B][T][2048] attn output
{
  const int tid  = threadIdx.x;
  const int wave = tid >> 6;   // 0..1
  const int lane = tid & 63;
  const int qd = lane >> 4, ln = lane & 15;
  const int p  = blockIdx.x;     // pair index 0..15 -> q-tiles {p, 31-p}
  const int h  = blockIdx.y;
  const int b  = blockIdx.z;
  const int hk = h >> 2;

  const __hip_bfloat16* K = qkv + (size_t)(b*TSEQ)*QKVC + CDIM + hk*HDIM;
  const __hip_bfloat16* V = vt + ((size_t)(b*NKV + hk)*HDIM)*TSEQ;

  __shared__ __align__(16) __hip_bfloat16 Ks[64*128];    // [t][d], swizzled
  __shared__ __align__(16) __hip_bfloat16 Vs[128*64];    // [d][t], swizzled
  __shared__ __align__(16) __hip_bfloat16 Pb[2*32*64];   // per-wave P, swizzled

  auto issueK = [&](int t0) {
#pragma unroll
    for (int i = 0; i < 8; ++i) {
      int c = i*128 + tid;             // chunk; 16 chunks/row
      int row = c >> 4, cc = c & 15;
      int gcc = cc ^ (row & 15);
      async16(&K[(size_t)(t0 + row)*QKVC + gcc*8], &Ks[(i*128 + wave*64)*8]);
    }
  };
  auto issueV = [&](int t0) {
#pragma unroll
    for (int i = 0; i < 8; ++i) {
      int c = i*128 + tid;             // chunk; 8 chunks/row
      int row = c >> 3, cc = c & 7;
      int gcc = cc ^ (row & 7);
      async16(&V[(size_t)row*TSEQ + t0 + gcc*8], &Vs[(i*128 + wave*64)*8]);
    }
  };

#pragma unroll 1
  for (int seg = 0; seg < 2; ++seg) {
    const int qt = seg ? (31 - p) : p;
    const int q0 = qt * 64;
    const int qws = q0 + wave * 32;    // this wave's 32 q-rows

    bf16x8 qfr[2][4];
#pragma unroll
    for (int sub = 0; sub < 2; ++sub)
#pragma unroll
      for (int kc = 0; kc < 4; ++kc)
        qfr[sub][kc] = *(const bf16x8*)&qkv[((size_t)(b*TSEQ + qws + sub*16 + ln))*QKVC + h*HDIM + kc*32 + qd*8];

    f32x4 o[2][8] = {};
    float lacc[2][4] = {};

    __syncthreads();          // Ks free (prev segment's epilogue readback done)
    issueK(0);
    __syncthreads();          // drain K[0]

#pragma unroll 1
    for (int kt = 0; kt <= qt; ++kt) {
      const int t0 = kt * 64;
      issueV(t0);             // Vs free: PV[kt-1] done by all at loop-end sync

      f32x4 sc[2][4] = {};
#pragma unroll
      for (int nt = 0; nt < 4; ++nt) {
#pragma unroll
        for (int kc = 0; kc < 4; ++kc) {
          bf16x8 kfr = *(const bf16x8*)&Ks[swz128(nt*16 + ln, kc*32 + qd*8)];
          sc[0][nt] = mfma16(qfr[0][kc], kfr, sc[0][nt]);
          sc[1][nt] = mfma16(qfr[1][kc], kfr, sc[1][nt]);
        }
      }
      if (t0 + 63 > qws) {    // causal mask touches this wave's rows
#pragma unroll
        for (int sub = 0; sub < 2; ++sub)
#pragma unroll
          for (int nt = 0; nt < 4; ++nt)
#pragma unroll
            for (int r = 0; r < 4; ++r) {
              int row = qws + sub*16 + qd*4 + r;
              int col = t0 + nt*16 + ln;
              if (col > row) sc[sub][nt][r] = -1.0e30f;
            }
      }
      // fixed-offset softmax: p = exp(s), defer l reduction
#pragma unroll
      for (int sub = 0; sub < 2; ++sub) {
#pragma unroll
        for (int nt = 0; nt < 4; ++nt)
#pragma unroll
          for (int r = 0; r < 4; ++r)
            sc[sub][nt][r] = __expf(sc[sub][nt][r]);
#pragma unroll
        for (int r = 0; r < 4; ++r)
          lacc[sub][r] += (sc[sub][0][r] + sc[sub][1][r]) + (sc[sub][2][r] + sc[sub][3][r]);
      }

      __hip_bfloat16* Pw = &Pb[wave*2048];
#pragma unroll
      for (int sub = 0; sub < 2; ++sub)
#pragma unroll
        for (int nt = 0; nt < 4; ++nt)
#pragma unroll
          for (int r = 0; r < 4; ++r)
            Pw[swz64(sub*16 + qd*4 + r, nt*16 + ln)] = __float2bfloat16(sc[sub][nt][r]);
      bf16x8 pa[2][2];
#pragma unroll
      for (int sub = 0; sub < 2; ++sub)
#pragma unroll
        for (int kc = 0; kc < 2; ++kc)
          pa[sub][kc] = *(const bf16x8*)&Pw[swz64(sub*16 + ln, kc*32 + qd*8)];

      __syncthreads();        // drain V[kt]; all waves done QK -> Ks free
      if (kt < qt) issueK(t0 + 64);   // overlaps PV

#pragma unroll
      for (int dt = 0; dt < 8; ++dt) {
#pragma unroll
        for (int kc = 0; kc < 2; ++kc) {
          bf16x8 vf = *(const bf16x8*)&Vs[swz64(dt*16 + ln, kc*32 + qd*8)];
          o[0][dt] = mfma16(pa[0][kc], vf, o[0][dt]);
          o[1][dt] = mfma16(pa[1][kc], vf, o[1][dt]);
        }
      }
      __syncthreads();        // drain K[kt+1]; all waves done PV -> Vs free
    }

    float inv[2][4];
#pragma unroll
    for (int sub = 0; sub < 2; ++sub)
#pragma unroll
      for (int r = 0; r < 4; ++r) {
        float lr = lacc[sub][r];
        lr += __shfl_xor(lr, 1);
        lr += __shfl_xor(lr, 2);
        lr += __shfl_xor(lr, 4);
        lr += __shfl_xor(lr, 8);
        inv[sub][r] = 1.0f / lr;
      }

    // coalesced epilogue via LDS (reuse Ks; wave-private 32x128 region)
    __hip_bfloat16* Ow = &Ks[wave*4096];
#pragma unroll
    for (int sub = 0; sub < 2; ++sub)
#pragma unroll
      for (int dt = 0; dt < 8; ++dt)
#pragma unroll
        for (int r = 0; r < 4; ++r)
          Ow[(sub*16 + qd*4 + r)*128 + dt*16 + ln] = __float2bfloat16(o[sub][dt][r] * inv[sub][r]);
    __syncthreads();          // writes visible before readback
#pragma unroll
    for (int pass = 0; pass < 8; ++pass) {
      int row = pass*4 + qd;
      bf16x8 val = *(const bf16x8*)&Ow[row*128 + ln*8];
      int q = qws + row;
      *(bf16x8*)&out[((size_t)(b*TSEQ + q))*CDIM + h*HDIM + ln*8] = val;
    }
  }
}

extern "C" void kernel_launch(void* const* d_in, const int* in_sizes, int n_in,
                              void* d_out, int out_size, void* d_ws, size_t ws_size,
                              hipStream_t stream) {
  char* ws = (char*)d_ws;
  size_t off = 0;
  auto alloc = [&](size_t bytes) { char* p = ws + off; off += (bytes + 255) & ~(size_t)255; return p; };

  int* flag = (int*)alloc(256);
  __hip_bfloat16* xb   = (__hip_bfloat16*)alloc((size_t)MROWS*CDIM*2);   // 16.8 MB (x, then attn out)
  __hip_bfloat16* wqkv = (__hip_bfloat16*)alloc((size_t)QKVC*CDIM*2);    // 12.6 MB
  __hip_bfloat16* wob  = (__hip_bfloat16*)alloc((size_t)CDIM*CDIM*2);    //  8.4 MB
  __hip_bfloat16* gb   = (__hip_bfloat16*)alloc(256);
  __hip_bfloat16* qkv  = (__hip_bfloat16*)alloc((size_t)MROWS*QKVC*2);   // 25.2 MB
  __hip_bfloat16* vt   = (__hip_bfloat16*)alloc((size_t)MROWS*KVC*2);    //  4.2 MB

  canary<<<1, 256, 0, stream>>>(d_in[0], flag);

  canonize_all<<<9217, 256, 0, stream>>>(
      d_in[0], d_in[1], d_in[2], d_in[3], d_in[4], d_in[5],
      xb, wqkv, wob, gb, flag);

  // fused QKV projection: [4096][2048] x [3072][2048]^T -> [4096][3072]
  gemm_bt256<<<dim3(QKVC/256, MROWS/256), 512, 0, stream>>>(
      xb, wqkv, qkv, MROWS, QKVC, CDIM, CDIM);

  int nwaves = MROWS*NH + MROWS*NKV;
  prep_qk<<<nwaves/4, 256, 0, stream>>>(qkv, gb);

  transpose_v<<<dim3(MROWS/32, KVC/32), 256, 0, stream>>>(qkv, vt);

  // attention: balanced pairs {p, 31-p}, 128-thread blocks, 2 waves x 32 rows
  attn_kernel<<<dim3(16, NH, BATCH), 128, 0, stream>>>(qkv, vt, xb);

  // output projection reads compact attn output (lda = 2048)
  gemm_out<<<dim3(CDIM/128, MROWS/128), 256, 0, stream>>>(
      xb, wob, d_out, MROWS, CDIM, CDIM, CDIM, flag);
}

// Round 4
// 294.488 us; speedup vs baseline: 1.1840x; 1.1840x over previous
//
#include <hip/hip_runtime.h>
#include <hip/hip_bf16.h>

#define TSEQ 2048
#define CDIM 2048
#define NH   16
#define NKV  4
#define HDIM 128
#define BATCH 2
#define MROWS (BATCH*TSEQ)   // 4096
#define KVC   (NKV*HDIM)     // 512
#define QKVC  (CDIM + 2*KVC) // 3072: fused qkv row stride

typedef short bf16x8 __attribute__((ext_vector_type(8)));
typedef float f32x4  __attribute__((ext_vector_type(4)));

typedef const __attribute__((address_space(1))) void* gptr_t;
typedef __attribute__((address_space(3))) void* sptr_t;

__device__ inline void async16(const __hip_bfloat16* g, __hip_bfloat16* l) {
  __builtin_amdgcn_global_load_lds((gptr_t)g, (sptr_t)l, 16, 0, 0);
}

__device__ inline f32x4 mfma16(bf16x8 a, bf16x8 b, f32x4 c) {
  return __builtin_amdgcn_mfma_f32_16x16x32_bf16(a, b, c, 0, 0, 0);
}

__device__ inline float bfbits2f(unsigned short u) {
  return __uint_as_float(((unsigned)u) << 16);
}

__device__ inline unsigned short f2bfu(float x) {
  __hip_bfloat16 t = __float2bfloat16(x);
  return *(unsigned short*)&t;
}

// LDS XOR-swizzles: break row-stride bank aliasing for 16B fragment access.
__device__ inline int swz128(int row, int col) {  // rows of 128 bf16
  return row*128 + (((col >> 3) ^ (row & 15)) << 3) + (col & 7);
}
__device__ inline int swz64(int row, int col) {   // rows of 64 bf16
  return row*64 + ((((col >> 3) ^ row) & 7) << 3) + (col & 7);
}

// ---- dtype canary: inputs bf16 (flag=1) or f32 (flag=0) ----
__global__ void canary(const void* __restrict__ x, int* __restrict__ flag) {
  __shared__ int cnt[256];
  int tid = threadIdx.x;
  const unsigned short* u = (const unsigned short*)x;
  int c = 0;
#pragma unroll
  for (int i = 0; i < 4; ++i) {
    float a = fabsf(bfbits2f(u[(tid*4 + i)*2]));
    if (a >= 1e-6f && a <= 1e3f) c++;
  }
  cnt[tid] = c;
  __syncthreads();
  for (int s = 128; s > 0; s >>= 1) {
    if (tid < s) cnt[tid] += cnt[tid + s];
    __syncthreads();
  }
  if (tid == 0) *flag = (cnt[0] > 512) ? 1 : 0;
}

// ---- canonize ALL inputs in one launch; Wq/Wk/Wv land contiguously ----
// Segments (2048-elem blocks): x:4096 | Wq:2048 | Wk:512 | Wv:512 | Wo:2048 | gain:1
__global__ __launch_bounds__(256) void canonize_all(
    const void* __restrict__ xs,  const void* __restrict__ wqs,
    const void* __restrict__ wks, const void* __restrict__ wvs,
    const void* __restrict__ wos, const void* __restrict__ gs,
    __hip_bfloat16* __restrict__ xd,   // [4096][2048]
    __hip_bfloat16* __restrict__ wqkv, // [3072][2048] (Wq;Wk;Wv rows)
    __hip_bfloat16* __restrict__ wod,  // [2048][2048]
    __hip_bfloat16* __restrict__ gd,   // [16]
    const int* __restrict__ flag)
{
  int blk = blockIdx.x;
  const void* src; __hip_bfloat16* dst; int base, n;
  if      (blk < 4096) { src = xs;  dst = xd;                base = blk;        n = MROWS*CDIM; }
  else if (blk < 6144) { src = wqs; dst = wqkv;              base = blk - 4096; n = CDIM*CDIM; }
  else if (blk < 6656) { src = wks; dst = wqkv + (size_t)CDIM*CDIM;            base = blk - 6144; n = KVC*CDIM; }
  else if (blk < 7168) { src = wvs; dst = wqkv + (size_t)(CDIM+KVC)*CDIM;      base = blk - 6656; n = KVC*CDIM; }
  else if (blk < 9216) { src = wos; dst = wod;               base = blk - 7168; n = CDIM*CDIM; }
  else                 { src = gs;  dst = gd;                base = 0;          n = NH; }
  int idx = base*2048 + threadIdx.x*8;
  if (idx >= n) return;
  if (*flag) {
    *(bf16x8*)&dst[idx] = *(const bf16x8*)((const __hip_bfloat16*)src + idx);
  } else {
    const float* s = (const float*)src + idx;
#pragma unroll
    for (int j = 0; j < 8; ++j) dst[idx + j] = __float2bfloat16(s[j]);
  }
}

// ---------------------------------------------------------------------------
// 256x256 BK=64 phase-split GEMM (T2 swizzle + T3/T4 counted-vmcnt + T5).
// C[m,n] = sum_k A[m,k]*B[n,k]; A row stride lda, B row stride K.
// ---------------------------------------------------------------------------
#define BK 64

__global__ __launch_bounds__(512, 2) void gemm_bt256(
    const __hip_bfloat16* __restrict__ A,
    const __hip_bfloat16* __restrict__ B,
    __hip_bfloat16* __restrict__ C,
    int M, int N, int K, int lda)
{
  __shared__ __align__(16) __hip_bfloat16 As[2][256*BK];  // 64 KiB
  __shared__ __align__(16) __hip_bfloat16 Bs[2][256*BK];  // 64 KiB
  const int tid  = threadIdx.x;
  const int wave = tid >> 6;
  const int lane = tid & 63;
  const int qd   = lane >> 4;
  const int ln   = lane & 15;
  const int m0   = blockIdx.y * 256;
  const int n0   = blockIdx.x * 256;
  const int wm   = (wave >> 2) * 128;  // 2 wave-rows
  const int wn   = (wave & 3) * 64;    // 4 wave-cols

  auto stageA = [&](int half, int buf, int kt) {
    const __hip_bfloat16* src = A + (size_t)(m0 + half*128)*lda + kt*BK;
    __hip_bfloat16* dst = &As[buf][half*128*BK];
#pragma unroll
    for (int i = 0; i < 2; ++i) {
      int c = i*512 + tid;
      int row = c >> 3, sl = c & 7;
      int gs = sl ^ (row & 7);
      async16(&src[(size_t)row*lda + gs*8], &dst[(i*512 + wave*64)*8]);
    }
  };
  auto stageB = [&](int half, int buf, int kt) {
    const __hip_bfloat16* src = B + (size_t)(n0 + half*128)*K + kt*BK;
    __hip_bfloat16* dst = &Bs[buf][half*128*BK];
#pragma unroll
    for (int i = 0; i < 2; ++i) {
      int c = i*512 + tid;
      int row = c >> 3, sl = c & 7;
      int gs = sl ^ (row & 7);
      async16(&src[(size_t)row*K + gs*8], &dst[(i*512 + wave*64)*8]);
    }
  };
  auto ldA = [&](int buf, int m, int kk) -> bf16x8 {
    int row = wm + m*16 + ln;
    return *(const bf16x8*)&As[buf][row*BK + (((kk*4 + qd) ^ (row & 7)) << 3)];
  };
  auto ldB = [&](int buf, int n, int kk) -> bf16x8 {
    int row = wn + n*16 + ln;
    return *(const bf16x8*)&Bs[buf][row*BK + (((kk*4 + qd) ^ (row & 7)) << 3)];
  };

  f32x4 acc[8][4] = {};
  const int nt = K / BK;

  stageA(0, 0, 0); stageA(1, 0, 0);
  stageB(0, 0, 0); stageB(1, 0, 0);
  if (nt > 1) {
    stageA(0, 1, 1); stageA(1, 1, 1);
    asm volatile("s_waitcnt vmcnt(4)" ::: "memory");
  } else {
    asm volatile("s_waitcnt vmcnt(0)" ::: "memory");
  }
  __builtin_amdgcn_s_barrier();

#pragma unroll 1
  for (int t = 0; t < nt; ++t) {
    const int buf = t & 1;
    bf16x8 a03[4][2], a47[4][2], b01[2][2], b23[2][2];

    // ---- P1 ----
#pragma unroll
    for (int m = 0; m < 4; ++m)
#pragma unroll
      for (int kk = 0; kk < 2; ++kk) a03[m][kk] = ldA(buf, m, kk);
#pragma unroll
    for (int n = 0; n < 2; ++n)
#pragma unroll
      for (int kk = 0; kk < 2; ++kk) b01[n][kk] = ldB(buf, n, kk);
    if (t + 1 < nt) { stageB(0, buf ^ 1, t + 1); stageB(1, buf ^ 1, t + 1); }
    __builtin_amdgcn_s_setprio(1);
#pragma unroll
    for (int m = 0; m < 4; ++m)
#pragma unroll
      for (int n = 0; n < 2; ++n)
#pragma unroll
        for (int kk = 0; kk < 2; ++kk)
          acc[m][n] = mfma16(a03[m][kk], b01[n][kk], acc[m][n]);
    __builtin_amdgcn_s_setprio(0);
    __builtin_amdgcn_s_barrier();

    // ---- P2 ----
#pragma unroll
    for (int m = 0; m < 4; ++m)
#pragma unroll
      for (int kk = 0; kk < 2; ++kk) a47[m][kk] = ldA(buf, 4 + m, kk);
    __builtin_amdgcn_s_setprio(1);
#pragma unroll
    for (int m = 0; m < 4; ++m)
#pragma unroll
      for (int n = 0; n < 2; ++n)
#pragma unroll
        for (int kk = 0; kk < 2; ++kk)
          acc[4 + m][n] = mfma16(a47[m][kk], b01[n][kk], acc[4 + m][n]);
    __builtin_amdgcn_s_setprio(0);
    __builtin_amdgcn_s_barrier();

    // ---- P3 ----
#pragma unroll
    for (int n = 0; n < 2; ++n)
#pragma unroll
      for (int kk = 0; kk < 2; ++kk) b23[n][kk] = ldB(buf, 2 + n, kk);
    __builtin_amdgcn_s_setprio(1);
#pragma unroll
    for (int m = 0; m < 4; ++m)
#pragma unroll
      for (int n = 0; n < 2; ++n)
#pragma unroll
        for (int kk = 0; kk < 2; ++kk)
          acc[m][2 + n] = mfma16(a03[m][kk], b23[n][kk], acc[m][2 + n]);
    __builtin_amdgcn_s_setprio(0);
    __builtin_amdgcn_s_barrier();

    // ---- P4 ----
    if (t + 2 < nt) { stageA(0, buf, t + 2); stageA(1, buf, t + 2); }
    __builtin_amdgcn_s_setprio(1);
#pragma unroll
    for (int m = 0; m < 4; ++m)
#pragma unroll
      for (int n = 0; n < 2; ++n)
#pragma unroll
        for (int kk = 0; kk < 2; ++kk)
          acc[4 + m][2 + n] = mfma16(a47[m][kk], b23[n][kk], acc[4 + m][2 + n]);
    __builtin_amdgcn_s_setprio(0);
    if (t + 2 < nt) asm volatile("s_waitcnt vmcnt(4)" ::: "memory");
    else            asm volatile("s_waitcnt vmcnt(0)" ::: "memory");
    __builtin_amdgcn_s_barrier();
  }

#pragma unroll
  for (int m = 0; m < 8; ++m)
#pragma unroll
    for (int n = 0; n < 4; ++n) {
      int row = m0 + wm + m*16 + qd*4;
      int col = n0 + wn + n*16 + ln;
#pragma unroll
      for (int r = 0; r < 4; ++r)
        C[(size_t)(row + r)*N + col] = __float2bfloat16(acc[m][n][r]);
    }
}

// Output GEMM; epilogue dtype per flag (d_out matches input dtype).
__global__ __launch_bounds__(256, 2) void gemm_out(
    const __hip_bfloat16* __restrict__ A,
    const __hip_bfloat16* __restrict__ B,
    void* __restrict__ C,
    int M, int N, int K, int lda, const int* __restrict__ flag)
{
  __shared__ __align__(16) __hip_bfloat16 As[128*32];
  __shared__ __align__(16) __hip_bfloat16 Bs[128*32];
  const int tid  = threadIdx.x;
  const int wave = tid >> 6;
  const int lane = tid & 63;
  const int qd   = lane >> 4;
  const int ln   = lane & 15;
  const int m0   = blockIdx.y * 128;
  const int n0   = blockIdx.x * 128;
  const int wm   = (wave >> 1) * 64;
  const int wn   = (wave & 1) * 64;

  f32x4 acc[4][4] = {};

  for (int k0 = 0; k0 < K; k0 += 32) {
    __syncthreads();
#pragma unroll
    for (int r = 0; r < 2; ++r) {
      int e   = (r*256 + tid) * 8;
      int row = e >> 5;
      int col = e & 31;
      async16(&A[(size_t)(m0+row)*lda + k0 + col], &As[(size_t)(r*256 + wave*64)*8]);
      async16(&B[(size_t)(n0+row)*K   + k0 + col], &Bs[(size_t)(r*256 + wave*64)*8]);
    }
    __syncthreads();
    bf16x8 af[4], bfr[4];
#pragma unroll
    for (int i = 0; i < 4; ++i)
      af[i] = *(const bf16x8*)&As[(wm + i*16 + ln)*32 + qd*8];
#pragma unroll
    for (int j = 0; j < 4; ++j)
      bfr[j] = *(const bf16x8*)&Bs[(wn + j*16 + ln)*32 + qd*8];
#pragma unroll
    for (int i = 0; i < 4; ++i)
#pragma unroll
      for (int j = 0; j < 4; ++j)
        acc[i][j] = mfma16(af[i], bfr[j], acc[i][j]);
  }
  const bool isbf = (*flag != 0);
#pragma unroll
  for (int i = 0; i < 4; ++i)
#pragma unroll
    for (int j = 0; j < 4; ++j) {
      int row = m0 + wm + i*16 + qd*4;
      int col = n0 + wn + j*16 + ln;
#pragma unroll
      for (int r = 0; r < 4; ++r) {
        if (isbf) ((__hip_bfloat16*)C)[(size_t)(row + r)*N + col] = __float2bfloat16(acc[i][j][r]);
        else      ((float*)C)[(size_t)(row + r)*N + col] = acc[i][j][r];
      }
    }
}

// RMSNorm + RoPE + (gain/sqrt(HD) for q), in place on the fused qkv buffer.
__global__ __launch_bounds__(256) void prep_qk(
    __hip_bfloat16* __restrict__ qkv,  // [4096][3072]: q | k | v
    const __hip_bfloat16* __restrict__ gain)
{
  int wid  = blockIdx.x * 4 + (threadIdx.x >> 6);
  int lane = threadIdx.x & 63;
  bool isq = wid < MROWS*NH;
  int m, h;
  __hip_bfloat16* p;
  if (isq) { m = wid >> 4; h = wid & 15; p = qkv + (size_t)m*QKVC + h*HDIM; }
  else     { int w2 = wid - MROWS*NH; m = w2 >> 2; h = w2 & 3; p = qkv + (size_t)m*QKVC + CDIM + h*HDIM; }

  ushort2 raw = *(const ushort2*)((const unsigned short*)p + 2*lane);
  float e = bfbits2f(raw.x), o = bfbits2f(raw.y);
  float ss = e*e + o*o;
#pragma unroll
  for (int off = 32; off >= 1; off >>= 1) ss += __shfl_xor(ss, off);
  float rms = rsqrtf(ss * (1.0f/128.0f) + 1.1920928955078125e-07f);
  e *= rms; o *= rms;

  float theta = exp2f(-(float)(2*lane) * (1.0f/128.0f) * 13.287712379549449f);
  int t = m & (TSEQ-1);
  float fr = (float)t * theta;
  float c = cosf(fr), s = sinf(fr);
  float re = e*c - o*s;
  float ro = e*s + o*c;

  if (isq) {
    float g = bfbits2f(*(const unsigned short*)&gain[h]) * 0.08838834764831845f;
    re *= g; ro *= g;
  }
  p[2*lane]   = __float2bfloat16(re);
  p[2*lane+1] = __float2bfloat16(ro);
}

// v section of qkv [4096][3072] -> vt [B][NKV][HDIM][TSEQ]
__global__ __launch_bounds__(256) void transpose_v(
    const __hip_bfloat16* __restrict__ qkv, __hip_bfloat16* __restrict__ vt)
{
  __shared__ __hip_bfloat16 tile[32][34];
  int tx = threadIdx.x & 31;
  int ty = threadIdx.x >> 5;
  int r0 = blockIdx.x * 32;
  int c0 = blockIdx.y * 32;
#pragma unroll
  for (int i = 0; i < 4; ++i)
    tile[ty + i*8][tx] = qkv[(size_t)(r0 + ty + i*8)*QKVC + (CDIM + KVC) + c0 + tx];
  __syncthreads();
  int b = r0 >> 11;
  int t = r0 & (TSEQ-1);
  int hk = c0 >> 7;
  int d0 = c0 & (HDIM-1);
#pragma unroll
  for (int i = 0; i < 4; ++i) {
    int d = d0 + ty + i*8;
    vt[((size_t)((b*NKV + hk)*HDIM + d))*TSEQ + t + tx] = tile[tx][ty + i*8];
  }
}

// Flash attention v9: v6's balanced shell (pairs {p,31-p}, 4 waves, 256 thr,
// 8 waves/CU) with swapped-operand dataflow that removes the 4x K/V LDS-read
// redundancy (v6's measured bottleneck):
//  - QK^T swapped: S^T = mfma(A=K-slice, B=Q-regs). Wave w owns kv-rows
//    w*16..w*16+15 -> reads ONLY its 4 KB K-slice/iter; Q lives in VGPRs.
//  - PV d-split: O^T = mfma(A=V^T-slice, B=P^T). Wave w owns d-rows
//    w*32..w*32+31 -> reads ONLY its 4 KB V-slice/iter.
//  - P^T staged once in LDS as [q][kv] (swz64, 8B packed writes).
// Per-iter LDS: K16+V16+Pw8+Pr32+stage32 = 104 KB (v6: 176). Same MFMA
// count, same 2-barrier loop, same staging/balance. Fixed-offset softmax.
__global__ __launch_bounds__(256, 2) void attn_kernel(
    const __hip_bfloat16* __restrict__ qkv, // [B][T][3072] (read-only here)
    const __hip_bfloat16* __restrict__ vt,  // [B][NKV][HD][T]
    __hip_bfloat16* __restrict__ out)       // [B][T][2048] attn output
{
  const int tid  = threadIdx.x;
  const int wave = tid >> 6;   // 0..3
  const int lane = tid & 63;
  const int qd = lane >> 4, ln = lane & 15;
  const int p  = blockIdx.x;     // pair index 0..15 -> q-tiles {p, 31-p}
  const int h  = blockIdx.y;
  const int b  = blockIdx.z;
  const int hk = h >> 2;

  const __hip_bfloat16* K = qkv + (size_t)(b*TSEQ)*QKVC + CDIM + hk*HDIM;
  const __hip_bfloat16* V = vt + ((size_t)(b*NKV + hk)*HDIM)*TSEQ;

  __shared__ __align__(16) __hip_bfloat16 Ks[64*128];  // [t][d], swz128
  __shared__ __align__(16) __hip_bfloat16 Vs[128*64];  // [d][t], swz64
  __shared__ __align__(16) __hip_bfloat16 Pb[64*64];   // P^T as [q][kv], swz64
  __shared__ float Lb[4][64];                          // per-wave l partials

  auto issueK = [&](int t0) {
#pragma unroll
    for (int i = 0; i < 4; ++i) {
      int c = i*256 + tid;             // chunk; 16 chunks/row
      int row = c >> 4, cc = c & 15;
      int gcc = cc ^ (row & 15);
      async16(&K[(size_t)(t0 + row)*QKVC + gcc*8], &Ks[(i*256 + wave*64)*8]);
    }
  };
  auto issueV = [&](int t0) {
#pragma unroll
    for (int i = 0; i < 4; ++i) {
      int c = i*256 + tid;             // chunk; 8 chunks/row
      int row = c >> 3, cc = c & 7;
      int gcc = cc ^ (row & 7);
      async16(&V[(size_t)row*TSEQ + t0 + gcc*8], &Vs[(i*256 + wave*64)*8]);
    }
  };

#pragma unroll 1
  for (int seg = 0; seg < 2; ++seg) {
    const int qt = seg ? (31 - p) : p;
    const int q0 = qt * 64;

    // Q as B-operand fragments (col q = qsub*16+ln, k = kc*32+qd*8+e)
    bf16x8 qfr[4][4];
#pragma unroll
    for (int qsub = 0; qsub < 4; ++qsub)
#pragma unroll
      for (int kc = 0; kc < 4; ++kc)
        qfr[qsub][kc] = *(const bf16x8*)&qkv[((size_t)(b*TSEQ + q0 + qsub*16 + ln))*QKVC + h*HDIM + kc*32 + qd*8];

    // O^T accumulator: o[half][qsub] holds O^T[d = wave*32+half*16+qd*4+r][q = qsub*16+ln]
    f32x4 o[2][4] = {};
    float lacc[4] = {0.f, 0.f, 0.f, 0.f};

    __syncthreads();          // Ks free (prev segment epilogue readback done)
    issueK(0);
    __syncthreads();          // drain K[0]

#pragma unroll 1
    for (int kt = 0; kt <= qt; ++kt) {
      const int t0 = kt * 64;
      issueV(t0);             // Vs free since prev iter-end barrier

      // ---- QK^T swapped: S^T[kv][q], wave owns kv-rows wave*16..+15 ----
      f32x4 sc[4] = {};
#pragma unroll
      for (int kc = 0; kc < 4; ++kc) {
        bf16x8 kfa = *(const bf16x8*)&Ks[swz128(wave*16 + ln, kc*32 + qd*8)];
#pragma unroll
        for (int qsub = 0; qsub < 4; ++qsub)
          sc[qsub] = mfma16(kfa, qfr[qsub][kc], sc[qsub]);
      }
      if (kt == qt) {  // diagonal: causal mask (D: row=kv=qd*4+r, col=q=ln)
#pragma unroll
        for (int qsub = 0; qsub < 4; ++qsub)
#pragma unroll
          for (int r = 0; r < 4; ++r) {
            int kv = t0 + wave*16 + qd*4 + r;
            int q  = q0 + qsub*16 + ln;
            if (kv > q) sc[qsub][r] = -1.0e30f;
          }
      }
      // fixed-offset softmax: p = exp(s), defer l reduction
#pragma unroll
      for (int qsub = 0; qsub < 4; ++qsub) {
#pragma unroll
        for (int r = 0; r < 4; ++r)
          sc[qsub][r] = __expf(sc[qsub][r]);
        lacc[qsub] += (sc[qsub][0] + sc[qsub][1]) + (sc[qsub][2] + sc[qsub][3]);
      }

      // write P^T to Pb[q][kv] (8B packed, swz64; kv = wave*16+qd*4+r)
#pragma unroll
      for (int qsub = 0; qsub < 4; ++qsub) {
        ushort4 pk;
        pk.x = f2bfu(sc[qsub][0]); pk.y = f2bfu(sc[qsub][1]);
        pk.z = f2bfu(sc[qsub][2]); pk.w = f2bfu(sc[qsub][3]);
        *(ushort4*)&Pb[swz64(qsub*16 + ln, wave*16 + qd*4)] = pk;
      }

      __syncthreads();        // P visible; V[kt] drained; Ks consumed by all
      if (kt < qt) issueK(t0 + 64);   // overlaps PV

      // ---- PV d-split: O^T[d][q] += V^T[d][kv] * P^T[kv][q] ----
      __builtin_amdgcn_s_setprio(1);
#pragma unroll
      for (int kc2 = 0; kc2 < 2; ++kc2) {
        bf16x8 pfb[4];
#pragma unroll
        for (int qsub = 0; qsub < 4; ++qsub)
          pfb[qsub] = *(const bf16x8*)&Pb[swz64(qsub*16 + ln, kc2*32 + qd*8)];
#pragma unroll
        for (int half = 0; half < 2; ++half) {
          bf16x8 vfa = *(const bf16x8*)&Vs[swz64(wave*32 + half*16 + ln, kc2*32 + qd*8)];
#pragma unroll
          for (int qsub = 0; qsub < 4; ++qsub)
            o[half][qsub] = mfma16(vfa, pfb[qsub], o[half][qsub]);
        }
      }
      __builtin_amdgcn_s_setprio(0);
      __syncthreads();        // drain K[kt+1]; Vs & Pb free
    }

    // l: reduce across qd groups (kv within wave), then across waves via LDS
#pragma unroll
    for (int qsub = 0; qsub < 4; ++qsub) {
      lacc[qsub] += __shfl_xor(lacc[qsub], 16);
      lacc[qsub] += __shfl_xor(lacc[qsub], 32);
    }
    if (qd == 0) {
#pragma unroll
      for (int qsub = 0; qsub < 4; ++qsub)
        Lb[wave][qsub*16 + ln] = lacc[qsub];
    }
    __syncthreads();
    float inv[4];
#pragma unroll
    for (int qsub = 0; qsub < 4; ++qsub) {
      int q = qsub*16 + ln;
      inv[qsub] = 1.0f / (((Lb[0][q] + Lb[1][q]) + (Lb[2][q] + Lb[3][q])));
    }

    // epilogue: Obuf = Ks reuse, [q 64][d 128] swz128; wave writes its d-cols
#pragma unroll
    for (int half = 0; half < 2; ++half)
#pragma unroll
      for (int qsub = 0; qsub < 4; ++qsub) {
        ushort4 pk;
        pk.x = f2bfu(o[half][qsub][0] * inv[qsub]);
        pk.y = f2bfu(o[half][qsub][1] * inv[qsub]);
        pk.z = f2bfu(o[half][qsub][2] * inv[qsub]);
        pk.w = f2bfu(o[half][qsub][3] * inv[qsub]);
        *(ushort4*)&Ks[swz128(qsub*16 + ln, wave*32 + half*16 + qd*4)] = pk;
      }
    __syncthreads();          // writes visible before readback
#pragma unroll
    for (int pass = 0; pass < 4; ++pass) {
      int row = wave*16 + pass*4 + qd;
      bf16x8 val = *(const bf16x8*)&Ks[swz128(row, ln*8)];
      int q = q0 + row;
      *(bf16x8*)&out[((size_t)(b*TSEQ + q))*CDIM + h*HDIM + ln*8] = val;
    }
  }
}

extern "C" void kernel_launch(void* const* d_in, const int* in_sizes, int n_in,
                              void* d_out, int out_size, void* d_ws, size_t ws_size,
                              hipStream_t stream) {
  char* ws = (char*)d_ws;
  size_t off = 0;
  auto alloc = [&](size_t bytes) { char* p = ws + off; off += (bytes + 255) & ~(size_t)255; return p; };

  int* flag = (int*)alloc(256);
  __hip_bfloat16* xb   = (__hip_bfloat16*)alloc((size_t)MROWS*CDIM*2);   // 16.8 MB (x, then attn out)
  __hip_bfloat16* wqkv = (__hip_bfloat16*)alloc((size_t)QKVC*CDIM*2);    // 12.6 MB
  __hip_bfloat16* wob  = (__hip_bfloat16*)alloc((size_t)CDIM*CDIM*2);    //  8.4 MB
  __hip_bfloat16* gb   = (__hip_bfloat16*)alloc(256);
  __hip_bfloat16* qkv  = (__hip_bfloat16*)alloc((size_t)MROWS*QKVC*2);   // 25.2 MB
  __hip_bfloat16* vt   = (__hip_bfloat16*)alloc((size_t)MROWS*KVC*2);    //  4.2 MB

  canary<<<1, 256, 0, stream>>>(d_in[0], flag);

  canonize_all<<<9217, 256, 0, stream>>>(
      d_in[0], d_in[1], d_in[2], d_in[3], d_in[4], d_in[5],
      xb, wqkv, wob, gb, flag);

  // fused QKV projection: [4096][2048] x [3072][2048]^T -> [4096][3072]
  gemm_bt256<<<dim3(QKVC/256, MROWS/256), 512, 0, stream>>>(
      xb, wqkv, qkv, MROWS, QKVC, CDIM, CDIM);

  int nwaves = MROWS*NH + MROWS*NKV;
  prep_qk<<<nwaves/4, 256, 0, stream>>>(qkv, gb);

  transpose_v<<<dim3(MROWS/32, KVC/32), 256, 0, stream>>>(qkv, vt);

  // attention: balanced pairs {p, 31-p}, 256-thread blocks, swapped-operand
  attn_kernel<<<dim3(16, NH, BATCH), 256, 0, stream>>>(qkv, vt, xb);

  // output projection reads compact attn output (lda = 2048)
  gemm_out<<<dim3(CDIM/128, MROWS/128), 256, 0, stream>>>(
      xb, wob, d_out, MROWS, CDIM, CDIM, CDIM, flag);
}